// Round 1
// baseline (461.903 us; speedup 1.0000x reference)
//
#include <hip/hip_runtime.h>

#define N_NODES 65536
#define N_EDGES 1048576
#define DIM     64
#define B_GRAPHS 32
#define NPG     2048
#define EPS_GN  1e-5f
#define SLOPE   0.01f

// ---------------- degree histogram ----------------
__global__ __launch_bounds__(256) void deg_kernel(const int* __restrict__ src,
                                                  const int* __restrict__ dst,
                                                  int* __restrict__ deg_out,
                                                  int* __restrict__ deg_in) {
    int e = blockIdx.x * 256 + threadIdx.x;
    if (e < N_EDGES) {
        atomicAdd(&deg_out[src[e]], 1);
        atomicAdd(&deg_in[dst[e]], 1);
    }
}

__global__ __launch_bounds__(256) void inv_kernel(const int* __restrict__ deg_out,
                                                  const int* __restrict__ deg_in,
                                                  float* __restrict__ inv_so,
                                                  float* __restrict__ inv_si) {
    int n = blockIdx.x * 256 + threadIdx.x;
    if (n < N_NODES) {
        inv_so[n] = rsqrtf((float)max(deg_out[n], 1));
        inv_si[n] = rsqrtf((float)max(deg_in[n], 1));
    }
}

// ---------------- exclusive prefix sum of deg_in (3-stage) ----------------
__global__ __launch_bounds__(256) void scan_block_kernel(const int* __restrict__ deg,
                                                         int* __restrict__ incl,
                                                         int* __restrict__ blockSums) {
    __shared__ int s[256];
    int tid = threadIdx.x;
    int gid = blockIdx.x * 256 + tid;
    s[tid] = deg[gid];
    __syncthreads();
    for (int off = 1; off < 256; off <<= 1) {
        int t = (tid >= off) ? s[tid - off] : 0;
        __syncthreads();
        s[tid] += t;
        __syncthreads();
    }
    incl[gid] = s[tid];
    if (tid == 255) blockSums[blockIdx.x] = s[255];
}

__global__ __launch_bounds__(256) void scan_top_kernel(int* __restrict__ blockSums) {
    __shared__ int s[256];
    int tid = threadIdx.x;
    s[tid] = blockSums[tid];
    __syncthreads();
    for (int off = 1; off < 256; off <<= 1) {
        int t = (tid >= off) ? s[tid - off] : 0;
        __syncthreads();
        s[tid] += t;
        __syncthreads();
    }
    blockSums[tid] = s[tid];
}

__global__ __launch_bounds__(256) void scan_add_kernel(const int* __restrict__ deg,
                                                       int* __restrict__ rowp,  // holds inclusive, becomes exclusive
                                                       const int* __restrict__ blockSums,
                                                       int* __restrict__ cursor) {
    int tid = threadIdx.x, b = blockIdx.x;
    int gid = b * 256 + tid;
    int off = (b > 0) ? blockSums[b - 1] : 0;
    int start = rowp[gid] - deg[gid] + off;
    rowp[gid] = start;
    cursor[gid] = start;
}

// ---------------- CSR fill (dst-sorted edge list, payload packed) ----------------
__global__ __launch_bounds__(256) void fill_kernel(const int* __restrict__ src,
                                                   const int* __restrict__ dst,
                                                   const float* __restrict__ ew,
                                                   int* __restrict__ cursor,
                                                   int* __restrict__ csr_src,
                                                   float* __restrict__ csr_w) {
    int e = blockIdx.x * 256 + threadIdx.x;
    if (e < N_EDGES) {
        int d = dst[e];
        int idx = atomicAdd(&cursor[d], 1);
        csr_src[idx] = src[e];
        csr_w[idx] = ew[e];
    }
}

// ---------------- dense: out[r][c] = sum_k f(in[r][k]) * W[k][c] ----------------
// f(v) = (alpha ? alpha[k]*v+beta[k] : v) * inv_so[r]
__global__ __launch_bounds__(256) void gemm_kernel(const float* __restrict__ in,
                                                   const float* __restrict__ W,
                                                   const float* __restrict__ inv_so,
                                                   const float* __restrict__ alpha,
                                                   const float* __restrict__ beta,
                                                   float* __restrict__ out) {
    __shared__ float wlds[64][64];   // W[k][c]
    __shared__ float xlds[16][64];   // 16 rows of transformed input
    int tid = threadIdx.x;
    for (int i = tid; i < 4096; i += 256)
        wlds[i >> 6][i & 63] = W[i];
    int r0 = blockIdx.x * 16;
    for (int i = tid; i < 1024; i += 256) {
        int r = i >> 6, k = i & 63;
        int gr = r0 + r;
        float v = in[(size_t)gr * 64 + k];
        if (alpha) v = alpha[k] * v + beta[k];
        xlds[r][k] = v * inv_so[gr];
    }
    __syncthreads();
    int c = tid & 63;
    int rg = tid >> 6;  // 0..3 -> rows rg*4..rg*4+3
    float acc[4] = {0.f, 0.f, 0.f, 0.f};
    for (int k = 0; k < 64; ++k) {
        float wv = wlds[k][c];
#pragma unroll
        for (int j = 0; j < 4; ++j)
            acc[j] += xlds[rg * 4 + j][k] * wv;
    }
#pragma unroll
    for (int j = 0; j < 4; ++j)
        out[(size_t)(r0 + rg * 4 + j) * 64 + c] = acc[j];
}

// ---------------- pull-aggregation + inv_si scale + LeakyReLU ----------------
// one wave per node, lane = feature
__global__ __launch_bounds__(256) void agg_kernel(const float* __restrict__ t,
                                                  const int* __restrict__ rowp,
                                                  const int* __restrict__ deg_in,
                                                  const float* __restrict__ inv_si,
                                                  const int* __restrict__ csr_src,
                                                  const float* __restrict__ csr_w,
                                                  float* __restrict__ y) {
    int tid = threadIdx.x;
    int node = blockIdx.x * 4 + (tid >> 6);
    int lane = tid & 63;
    int start = rowp[node];
    int cnt = deg_in[node];
    float acc = 0.f;
    for (int i = 0; i < cnt; ++i) {
        int s = csr_src[start + i];
        float w = csr_w[start + i];
        acc += t[(size_t)s * 64 + lane] * w;
    }
    float v = acc * inv_si[node];
    v = (v >= 0.f) ? v : SLOPE * v;
    y[(size_t)node * 64 + lane] = v;
}

// ---------------- per-feature sums for GraphNorm ----------------
__global__ __launch_bounds__(256) void stats_kernel(const float* __restrict__ y,
                                                    float* __restrict__ Sy,
                                                    float* __restrict__ Syy) {
    __shared__ float ls[4][64];
    __shared__ float lq[4][64];
    int tid = threadIdx.x;
    int lane = tid & 63, wave = tid >> 6;
    float s = 0.f, q = 0.f;
    int base = blockIdx.x * 256 + wave * 64;
    for (int i = 0; i < 64; ++i) {
        float v = y[(size_t)(base + i) * 64 + lane];
        s += v;
        q += v * v;
    }
    ls[wave][lane] = s;
    lq[wave][lane] = q;
    __syncthreads();
    if (wave == 0) {
        float ts = ls[0][lane] + ls[1][lane] + ls[2][lane] + ls[3][lane];
        float tq = lq[0][lane] + lq[1][lane] + lq[2][lane] + lq[3][lane];
        atomicAdd(&Sy[lane], ts);
        atomicAdd(&Syy[lane], tq);
    }
}

// GraphNorm(y) = alpha*y + beta, with var = E[y^2] - 2a m E[y] + a^2 m^2
__global__ void finalize_kernel(const float* __restrict__ Sy, const float* __restrict__ Syy,
                                const float* __restrict__ w, const float* __restrict__ b,
                                const float* __restrict__ a,
                                float* __restrict__ alpha, float* __restrict__ beta) {
    int f = threadIdx.x;
    if (f < 64) {
        float m = Sy[f] * (1.f / N_NODES);
        float q = Syy[f] * (1.f / N_NODES);
        float af = a[f];
        float var = q - 2.f * af * m * m + af * af * m * m;
        float stdv = sqrtf(var + EPS_GN);
        float al = w[f] / stdv;
        alpha[f] = al;
        beta[f] = b[f] - al * af * m;
    }
}

// ---------------- per-graph mean pool (contiguous 2048-node graphs) + GN affine ----------------
__global__ __launch_bounds__(256) void pool_kernel(const float* __restrict__ y,
                                                   const float* __restrict__ alpha,
                                                   const float* __restrict__ beta,
                                                   float* __restrict__ pooled) {
    __shared__ float ls[4][64];
    int tid = threadIdx.x;
    int lane = tid & 63, wave = tid >> 6;
    int g = blockIdx.x;
    float s = 0.f;
    int base = g * NPG + wave * 512;
    for (int i = 0; i < 512; ++i)
        s += y[(size_t)(base + i) * 64 + lane];
    ls[wave][lane] = s;
    __syncthreads();
    if (wave == 0) {
        float tot = ls[0][lane] + ls[1][lane] + ls[2][lane] + ls[3][lane];
        pooled[g * 64 + lane] = alpha[lane] * (tot * (1.f / NPG)) + beta[lane];
    }
}

// ---------------- final tiny GEMM: out[g][o] = sum_f pooled[g][f]*Wc[o][f] ----------------
__global__ __launch_bounds__(256) void out_kernel(const float* __restrict__ pooled,
                                                  const float* __restrict__ Wc,
                                                  float* __restrict__ out) {
    int tid = threadIdx.x;
    for (int idx = tid; idx < B_GRAPHS * 32; idx += 256) {
        int g = idx >> 5, o = idx & 31;
        float acc = 0.f;
        for (int f = 0; f < 64; ++f)
            acc += pooled[g * 64 + f] * Wc[o * 64 + f];
        out[idx] = acc;
    }
}

extern "C" void kernel_launch(void* const* d_in, const int* in_sizes, int n_in,
                              void* d_out, int out_size, void* d_ws, size_t ws_size,
                              hipStream_t stream) {
    const float* x     = (const float*)d_in[0];
    const float* ew    = (const float*)d_in[1];
    const float* W1    = (const float*)d_in[2];
    const float* W2    = (const float*)d_in[3];
    const float* Wc    = (const float*)d_in[4];
    const float* gn1_w = (const float*)d_in[5];
    const float* gn1_b = (const float*)d_in[6];
    const float* gn1_a = (const float*)d_in[7];
    const float* gn2_w = (const float*)d_in[8];
    const float* gn2_b = (const float*)d_in[9];
    const float* gn2_a = (const float*)d_in[10];
    const int* src     = (const int*)d_in[11];
    const int* dst     = (const int*)d_in[12];
    // d_in[13] graph_ids: contiguous blocks of NPG nodes per graph (arange // NPG)

    char* ws = (char*)d_ws;
    // zeroed region: [deg_out_i | deg_in_i | stats(4*64 f32)]
    int*   deg_out_i = (int*)(ws + 0);                 // 256 KB
    int*   deg_in_i  = (int*)(ws + 262144);            // 256 KB
    float* stats     = (float*)(ws + 524288);          // Sy1,Syy1,Sy2,Syy2 (1 KB)
    float* ab        = (float*)(ws + 525312);          // a1,b1,a2,b2 (1 KB)
    int*   topSums   = (int*)(ws + 526336);            // 1 KB
    float* inv_so    = (float*)(ws + (1u << 20));
    float* inv_si    = (float*)(ws + (1u << 20) + 262144);
    int*   rowp      = (int*)(ws + (1u << 20) + 524288);
    int*   cursor    = (int*)(ws + (1u << 20) + 786432);
    int*   csr_src   = (int*)(ws + (2u << 20));        // 4 MB
    float* csr_w     = (float*)(ws + (6u << 20));      // 4 MB
    float* bufA      = (float*)(ws + (10u << 20));     // 16 MB
    float* bufB      = (float*)(ws + (26u << 20));     // 16 MB
    float* pooled    = (float*)(ws + (42u << 20));     // 8 KB

    hipMemsetAsync(ws, 0, 525312 + 1024, stream);

    // graph structure (recomputed every call — deterministic inputs)
    deg_kernel<<<N_EDGES / 256, 256, 0, stream>>>(src, dst, deg_out_i, deg_in_i);
    inv_kernel<<<N_NODES / 256, 256, 0, stream>>>(deg_out_i, deg_in_i, inv_so, inv_si);
    scan_block_kernel<<<256, 256, 0, stream>>>(deg_in_i, rowp, topSums);
    scan_top_kernel<<<1, 256, 0, stream>>>(topSums);
    scan_add_kernel<<<256, 256, 0, stream>>>(deg_in_i, rowp, topSums, cursor);
    fill_kernel<<<N_EDGES / 256, 256, 0, stream>>>(src, dst, ew, cursor, csr_src, csr_w);

    // layer 1
    gemm_kernel<<<N_NODES / 16, 256, 0, stream>>>(x, W1, inv_so, nullptr, nullptr, bufA);
    agg_kernel<<<N_NODES / 4, 256, 0, stream>>>(bufA, rowp, deg_in_i, inv_si, csr_src, csr_w, bufB);
    stats_kernel<<<256, 256, 0, stream>>>(bufB, stats + 0, stats + 64);
    finalize_kernel<<<1, 64, 0, stream>>>(stats + 0, stats + 64, gn1_w, gn1_b, gn1_a, ab + 0, ab + 64);

    // layer 2 (GraphNorm-1 affine fused into GEMM2 load)
    gemm_kernel<<<N_NODES / 16, 256, 0, stream>>>(bufB, W2, inv_so, ab + 0, ab + 64, bufA);
    agg_kernel<<<N_NODES / 4, 256, 0, stream>>>(bufA, rowp, deg_in_i, inv_si, csr_src, csr_w, bufB);
    stats_kernel<<<256, 256, 0, stream>>>(bufB, stats + 128, stats + 192);
    finalize_kernel<<<1, 64, 0, stream>>>(stats + 128, stats + 192, gn2_w, gn2_b, gn2_a, ab + 128, ab + 192);

    // pool (GraphNorm-2 affine fused) + classifier
    pool_kernel<<<B_GRAPHS, 256, 0, stream>>>(bufB, ab + 128, ab + 192, pooled);
    out_kernel<<<1, 256, 0, stream>>>(pooled, Wc, (float*)d_out);
}

// Round 2
// 336.449 us; speedup vs baseline: 1.3729x; 1.3729x over previous
//
#include <hip/hip_runtime.h>

#define N_NODES 65536
#define N_EDGES 1048576
#define DIM     64
#define B_GRAPHS 32
#define NPG     2048
#define EPS_GN  1e-5f
#define SLOPE   0.01f

// ---------------- degree histogram (4 edges/thread, int4 loads) ----------------
__global__ __launch_bounds__(256) void deg_kernel(const int4* __restrict__ src4,
                                                  const int4* __restrict__ dst4,
                                                  int* __restrict__ deg_out,
                                                  int* __restrict__ deg_in) {
    int t = blockIdx.x * 256 + threadIdx.x;   // t < E/4
    int4 s = src4[t];
    int4 d = dst4[t];
    atomicAdd(&deg_out[s.x], 1);
    atomicAdd(&deg_out[s.y], 1);
    atomicAdd(&deg_out[s.z], 1);
    atomicAdd(&deg_out[s.w], 1);
    atomicAdd(&deg_in[d.x], 1);
    atomicAdd(&deg_in[d.y], 1);
    atomicAdd(&deg_in[d.z], 1);
    atomicAdd(&deg_in[d.w], 1);
}

// ---------------- exclusive prefix sum of deg_in (3-stage) ----------------
__global__ __launch_bounds__(256) void scan_block_kernel(const int* __restrict__ deg,
                                                         int* __restrict__ incl,
                                                         int* __restrict__ blockSums) {
    __shared__ int s[256];
    int tid = threadIdx.x;
    int gid = blockIdx.x * 256 + tid;
    s[tid] = deg[gid];
    __syncthreads();
    for (int off = 1; off < 256; off <<= 1) {
        int t = (tid >= off) ? s[tid - off] : 0;
        __syncthreads();
        s[tid] += t;
        __syncthreads();
    }
    incl[gid] = s[tid];
    if (tid == 255) blockSums[blockIdx.x] = s[255];
}

__global__ __launch_bounds__(256) void scan_top_kernel(int* __restrict__ blockSums) {
    __shared__ int s[256];
    int tid = threadIdx.x;
    s[tid] = blockSums[tid];
    __syncthreads();
    for (int off = 1; off < 256; off <<= 1) {
        int t = (tid >= off) ? s[tid - off] : 0;
        __syncthreads();
        s[tid] += t;
        __syncthreads();
    }
    blockSums[tid] = s[tid];
}

// exclusive offsets + cursor init + degree-normalization factors (merged)
__global__ __launch_bounds__(256) void scan_add_kernel(const int* __restrict__ deg_in,
                                                       const int* __restrict__ deg_out,
                                                       int* __restrict__ rowp,  // inclusive -> exclusive
                                                       const int* __restrict__ blockSums,
                                                       int* __restrict__ cursor,
                                                       float* __restrict__ inv_so,
                                                       float* __restrict__ inv_si) {
    int tid = threadIdx.x, b = blockIdx.x;
    int gid = b * 256 + tid;
    int off = (b > 0) ? blockSums[b - 1] : 0;
    int di = deg_in[gid];
    int start = rowp[gid] - di + off;
    rowp[gid] = start;
    cursor[gid] = start;
    inv_so[gid] = rsqrtf((float)max(deg_out[gid], 1));
    inv_si[gid] = rsqrtf((float)max(di, 1));
}

// ---------------- CSR fill: packed int2 {src, w_bits}, 4 edges/thread ----------------
__global__ __launch_bounds__(256) void fill_kernel(const int4* __restrict__ src4,
                                                   const int4* __restrict__ dst4,
                                                   const float4* __restrict__ ew4,
                                                   int* __restrict__ cursor,
                                                   int2* __restrict__ csr) {
    int t = blockIdx.x * 256 + threadIdx.x;   // t < E/4
    int4 s = src4[t];
    int4 d = dst4[t];
    float4 w = ew4[t];
    int i0 = atomicAdd(&cursor[d.x], 1); csr[i0] = make_int2(s.x, __float_as_int(w.x));
    int i1 = atomicAdd(&cursor[d.y], 1); csr[i1] = make_int2(s.y, __float_as_int(w.y));
    int i2 = atomicAdd(&cursor[d.z], 1); csr[i2] = make_int2(s.z, __float_as_int(w.z));
    int i3 = atomicAdd(&cursor[d.w], 1); csr[i3] = make_int2(s.w, __float_as_int(w.w));
}

// ---------------- dense: out[r][c] = sum_k f(in[r][k]) * W[k][c] ----------------
// f(v) = (alpha ? alpha[k]*v+beta[k] : v) * inv_so[r]
__global__ __launch_bounds__(256) void gemm_kernel(const float* __restrict__ in,
                                                   const float* __restrict__ W,
                                                   const float* __restrict__ inv_so,
                                                   const float* __restrict__ alpha,
                                                   const float* __restrict__ beta,
                                                   float* __restrict__ out) {
    __shared__ float wlds[64][64];   // W[k][c]
    __shared__ float xlds[16][64];   // 16 rows of transformed input
    int tid = threadIdx.x;
    for (int i = tid; i < 4096; i += 256)
        wlds[i >> 6][i & 63] = W[i];
    int r0 = blockIdx.x * 16;
    for (int i = tid; i < 1024; i += 256) {
        int r = i >> 6, k = i & 63;
        int gr = r0 + r;
        float v = in[(size_t)gr * 64 + k];
        if (alpha) v = alpha[k] * v + beta[k];
        xlds[r][k] = v * inv_so[gr];
    }
    __syncthreads();
    int c = tid & 63;
    int rg = tid >> 6;  // 0..3 -> rows rg*4..rg*4+3
    float acc[4] = {0.f, 0.f, 0.f, 0.f};
    for (int k = 0; k < 64; ++k) {
        float wv = wlds[k][c];
#pragma unroll
        for (int j = 0; j < 4; ++j)
            acc[j] += xlds[rg * 4 + j][k] * wv;
    }
#pragma unroll
    for (int j = 0; j < 4; ++j)
        out[(size_t)(r0 + rg * 4 + j) * 64 + c] = acc[j];
}

// ---------------- pull-aggregation + inv_si scale + LeakyReLU ----------------
// 16 lanes per node, float4 per lane; 4 node-chains per wave; edge loop unrolled x4
__global__ __launch_bounds__(256) void agg_kernel(const float4* __restrict__ T4,   // [N][16] float4
                                                  const int* __restrict__ rowp,
                                                  const int* __restrict__ deg_in,
                                                  const float* __restrict__ inv_si,
                                                  const int2* __restrict__ csr,
                                                  float4* __restrict__ Y4) {
    int tid = threadIdx.x;
    int node = blockIdx.x * 16 + (tid >> 4);
    int l16 = tid & 15;
    int start = rowp[node];
    int cnt = deg_in[node];
    const int2* ep = csr + start;
    float4 acc = make_float4(0.f, 0.f, 0.f, 0.f);
    int i = 0;
    for (; i + 4 <= cnt; i += 4) {
        int2 e0 = ep[i];
        int2 e1 = ep[i + 1];
        int2 e2 = ep[i + 2];
        int2 e3 = ep[i + 3];
        float4 a0 = T4[(size_t)e0.x * 16 + l16];
        float4 a1 = T4[(size_t)e1.x * 16 + l16];
        float4 a2 = T4[(size_t)e2.x * 16 + l16];
        float4 a3 = T4[(size_t)e3.x * 16 + l16];
        float w0 = __int_as_float(e0.y), w1 = __int_as_float(e1.y);
        float w2 = __int_as_float(e2.y), w3 = __int_as_float(e3.y);
        acc.x += a0.x * w0 + a1.x * w1 + a2.x * w2 + a3.x * w3;
        acc.y += a0.y * w0 + a1.y * w1 + a2.y * w2 + a3.y * w3;
        acc.z += a0.z * w0 + a1.z * w1 + a2.z * w2 + a3.z * w3;
        acc.w += a0.w * w0 + a1.w * w1 + a2.w * w2 + a3.w * w3;
    }
    for (; i < cnt; ++i) {
        int2 e = ep[i];
        float4 a = T4[(size_t)e.x * 16 + l16];
        float w = __int_as_float(e.y);
        acc.x += a.x * w;
        acc.y += a.y * w;
        acc.z += a.z * w;
        acc.w += a.w * w;
    }
    float s = inv_si[node];
    float4 v;
    v.x = acc.x * s; v.x = (v.x >= 0.f) ? v.x : SLOPE * v.x;
    v.y = acc.y * s; v.y = (v.y >= 0.f) ? v.y : SLOPE * v.y;
    v.z = acc.z * s; v.z = (v.z >= 0.f) ? v.z : SLOPE * v.z;
    v.w = acc.w * s; v.w = (v.w >= 0.f) ? v.w : SLOPE * v.w;
    Y4[(size_t)node * 16 + l16] = v;
}

// ---------------- per-feature sums for GraphNorm ----------------
__global__ __launch_bounds__(256) void stats_kernel(const float* __restrict__ y,
                                                    float* __restrict__ Sy,
                                                    float* __restrict__ Syy) {
    __shared__ float ls[4][64];
    __shared__ float lq[4][64];
    int tid = threadIdx.x;
    int lane = tid & 63, wave = tid >> 6;
    float s = 0.f, q = 0.f;
    int base = blockIdx.x * 256 + wave * 64;
    for (int i = 0; i < 64; ++i) {
        float v = y[(size_t)(base + i) * 64 + lane];
        s += v;
        q += v * v;
    }
    ls[wave][lane] = s;
    lq[wave][lane] = q;
    __syncthreads();
    if (wave == 0) {
        float ts = ls[0][lane] + ls[1][lane] + ls[2][lane] + ls[3][lane];
        float tq = lq[0][lane] + lq[1][lane] + lq[2][lane] + lq[3][lane];
        atomicAdd(&Sy[lane], ts);
        atomicAdd(&Syy[lane], tq);
    }
}

// GraphNorm(y) = alpha*y + beta, with var = E[y^2] - 2a m E[y] + a^2 m^2
__global__ void finalize_kernel(const float* __restrict__ Sy, const float* __restrict__ Syy,
                                const float* __restrict__ w, const float* __restrict__ b,
                                const float* __restrict__ a,
                                float* __restrict__ alpha, float* __restrict__ beta) {
    int f = threadIdx.x;
    if (f < 64) {
        float m = Sy[f] * (1.f / N_NODES);
        float q = Syy[f] * (1.f / N_NODES);
        float af = a[f];
        float var = q - 2.f * af * m * m + af * af * m * m;
        float stdv = sqrtf(var + EPS_GN);
        float al = w[f] / stdv;
        alpha[f] = al;
        beta[f] = b[f] - al * af * m;
    }
}

// ---------------- per-graph mean pool (contiguous 2048-node graphs) + GN affine ----------------
__global__ __launch_bounds__(256) void pool_kernel(const float* __restrict__ y,
                                                   const float* __restrict__ alpha,
                                                   const float* __restrict__ beta,
                                                   float* __restrict__ pooled) {
    __shared__ float ls[4][64];
    int tid = threadIdx.x;
    int lane = tid & 63, wave = tid >> 6;
    int g = blockIdx.x;
    float s = 0.f;
    int base = g * NPG + wave * 512;
    for (int i = 0; i < 512; ++i)
        s += y[(size_t)(base + i) * 64 + lane];
    ls[wave][lane] = s;
    __syncthreads();
    if (wave == 0) {
        float tot = ls[0][lane] + ls[1][lane] + ls[2][lane] + ls[3][lane];
        pooled[g * 64 + lane] = alpha[lane] * (tot * (1.f / NPG)) + beta[lane];
    }
}

// ---------------- final tiny GEMM: out[g][o] = sum_f pooled[g][f]*Wc[o][f] ----------------
__global__ __launch_bounds__(256) void out_kernel(const float* __restrict__ pooled,
                                                  const float* __restrict__ Wc,
                                                  float* __restrict__ out) {
    int tid = threadIdx.x;
    for (int idx = tid; idx < B_GRAPHS * 32; idx += 256) {
        int g = idx >> 5, o = idx & 31;
        float acc = 0.f;
        for (int f = 0; f < 64; ++f)
            acc += pooled[g * 64 + f] * Wc[o * 64 + f];
        out[idx] = acc;
    }
}

extern "C" void kernel_launch(void* const* d_in, const int* in_sizes, int n_in,
                              void* d_out, int out_size, void* d_ws, size_t ws_size,
                              hipStream_t stream) {
    const float* x     = (const float*)d_in[0];
    const float* ew    = (const float*)d_in[1];
    const float* W1    = (const float*)d_in[2];
    const float* W2    = (const float*)d_in[3];
    const float* Wc    = (const float*)d_in[4];
    const float* gn1_w = (const float*)d_in[5];
    const float* gn1_b = (const float*)d_in[6];
    const float* gn1_a = (const float*)d_in[7];
    const float* gn2_w = (const float*)d_in[8];
    const float* gn2_b = (const float*)d_in[9];
    const float* gn2_a = (const float*)d_in[10];
    const int* src     = (const int*)d_in[11];
    const int* dst     = (const int*)d_in[12];
    // d_in[13] graph_ids: contiguous blocks of NPG nodes per graph (arange // NPG)

    char* ws = (char*)d_ws;
    // zeroed region: [deg_out_i | deg_in_i | stats(4*64 f32)]
    int*   deg_out_i = (int*)(ws + 0);                 // 256 KB
    int*   deg_in_i  = (int*)(ws + 262144);            // 256 KB
    float* stats     = (float*)(ws + 524288);          // Sy1,Syy1,Sy2,Syy2 (1 KB)
    float* ab        = (float*)(ws + 525312);          // a1,b1,a2,b2 (1 KB)
    int*   topSums   = (int*)(ws + 526336);            // 1 KB
    float* inv_so    = (float*)(ws + (1u << 20));
    float* inv_si    = (float*)(ws + (1u << 20) + 262144);
    int*   rowp      = (int*)(ws + (1u << 20) + 524288);
    int*   cursor    = (int*)(ws + (1u << 20) + 786432);
    int2*  csr       = (int2*)(ws + (2u << 20));       // 8 MB packed {src, w}
    float* bufA      = (float*)(ws + (10u << 20));     // 16 MB
    float* bufB      = (float*)(ws + (26u << 20));     // 16 MB
    float* pooled    = (float*)(ws + (42u << 20));     // 8 KB

    hipMemsetAsync(ws, 0, 525312 + 1024, stream);

    // graph structure (recomputed every call — deterministic inputs)
    deg_kernel<<<N_EDGES / 4 / 256, 256, 0, stream>>>((const int4*)src, (const int4*)dst,
                                                      deg_out_i, deg_in_i);
    scan_block_kernel<<<256, 256, 0, stream>>>(deg_in_i, rowp, topSums);
    scan_top_kernel<<<1, 256, 0, stream>>>(topSums);
    scan_add_kernel<<<256, 256, 0, stream>>>(deg_in_i, deg_out_i, rowp, topSums, cursor,
                                             inv_so, inv_si);
    fill_kernel<<<N_EDGES / 4 / 256, 256, 0, stream>>>((const int4*)src, (const int4*)dst,
                                                       (const float4*)ew, cursor, csr);

    // layer 1
    gemm_kernel<<<N_NODES / 16, 256, 0, stream>>>(x, W1, inv_so, nullptr, nullptr, bufA);
    agg_kernel<<<N_NODES / 16, 256, 0, stream>>>((const float4*)bufA, rowp, deg_in_i, inv_si,
                                                 csr, (float4*)bufB);
    stats_kernel<<<256, 256, 0, stream>>>(bufB, stats + 0, stats + 64);
    finalize_kernel<<<1, 64, 0, stream>>>(stats + 0, stats + 64, gn1_w, gn1_b, gn1_a, ab + 0, ab + 64);

    // layer 2 (GraphNorm-1 affine fused into GEMM2 load)
    gemm_kernel<<<N_NODES / 16, 256, 0, stream>>>(bufB, W2, inv_so, ab + 0, ab + 64, bufA);
    agg_kernel<<<N_NODES / 16, 256, 0, stream>>>((const float4*)bufA, rowp, deg_in_i, inv_si,
                                                 csr, (float4*)bufB);
    stats_kernel<<<256, 256, 0, stream>>>(bufB, stats + 128, stats + 192);
    finalize_kernel<<<1, 64, 0, stream>>>(stats + 128, stats + 192, gn2_w, gn2_b, gn2_a, ab + 128, ab + 192);

    // pool (GraphNorm-2 affine fused) + classifier
    pool_kernel<<<B_GRAPHS, 256, 0, stream>>>(bufB, ab + 128, ab + 192, pooled);
    out_kernel<<<1, 256, 0, stream>>>(pooled, Wc, (float*)d_out);
}